// Round 1
// baseline (666.948 us; speedup 1.0000x reference)
//
#include <hip/hip_runtime.h>
#include <hip/hip_bf16.h>

#define E_ 16
#define D_ 4096
#define F_ 688
#define N_ 8192
#define CAP_ 640   // int(1.25 * 8192 / 16)

typedef __attribute__((ext_vector_type(8))) short bf16x8;
typedef __attribute__((ext_vector_type(4))) float f32x4;
typedef __attribute__((ext_vector_type(4))) float fvec4;
typedef __attribute__((ext_vector_type(4))) unsigned short usvec4;

__device__ __forceinline__ unsigned short f2bf(float f) {
    __hip_bfloat16 h = __float2bfloat16(f);
    return __builtin_bit_cast(unsigned short, h);
}

// ---------------- dispatch: stable per-expert positions ----------------
__global__ void k_dispatch(const int* __restrict__ idx,
                           int* __restrict__ slot_token,
                           int* __restrict__ row_of,
                           int* __restrict__ cnt) {
    __shared__ int hist[256][E_];
    const int t = threadIdx.x;
#pragma unroll
    for (int e = 0; e < E_; e++) hist[t][e] = 0;
    __syncthreads();
    const int base = t * (N_ / 256);
    for (int j = 0; j < N_ / 256; j++) {
        int e = idx[base + j];
        hist[t][e]++;
    }
    __syncthreads();
    if (t < E_) {
        int run = 0;
        for (int i = 0; i < 256; i++) { int v = hist[i][t]; hist[i][t] = run; run += v; }
        cnt[t] = run < CAP_ ? run : CAP_;
    }
    for (int s = t; s < E_ * CAP_; s += 256) slot_token[s] = -1;
    __syncthreads();
    for (int j = 0; j < N_ / 256; j++) {
        int i = base + j;
        int e = idx[i];
        int p = hist[t][e]++;
        if (p < CAP_) { slot_token[e * CAP_ + p] = i; row_of[i] = e * CAP_ + p; }
        else          { row_of[i] = -1; }
    }
}

// ---------------- zero the (rare) dropped-token rows ----------------
__global__ void k_zero_dropped(const int* __restrict__ row_of, float* __restrict__ y) {
    const int i = blockIdx.x;
    if (row_of[i] >= 0) return;
    fvec4* yp = (fvec4*)(y + (size_t)i * D_);
    fvec4 z = {0.f, 0.f, 0.f, 0.f};
    for (int c = threadIdx.x; c < D_ / 4; c += 256) yp[c] = z;
}

// ---------------- GEMM1: H = silu(X*Wg) * (X*Wu), bf16 out ----------------
__global__ __launch_bounds__(256, 2) void k_gemm1(
    const float* __restrict__ x, const float* __restrict__ Wg, const float* __restrict__ Wu,
    const int* __restrict__ slot_token, const int* __restrict__ cnt,
    unsigned short* __restrict__ H) {
    const int e = blockIdx.z, m0 = blockIdx.y * 128, f0 = blockIdx.x * 64;
    if (m0 >= cnt[e]) return;

    __shared__ __align__(16) unsigned short As[128 * 72];
    __shared__ __align__(16) unsigned short Bgs[64 * 72];
    __shared__ __align__(16) unsigned short Bus[64 * 72];
    __shared__ int tokS[128];

    const int tid = threadIdx.x;
    const int lane = tid & 63, wave = tid >> 6;
    const int wm = wave >> 1, wn = wave & 1;

    if (tid < 128) tokS[tid] = slot_token[e * CAP_ + m0 + tid];
    __syncthreads();

    f32x4 accG[4][2], accU[4][2];
#pragma unroll
    for (int a = 0; a < 4; a++)
#pragma unroll
        for (int b = 0; b < 2; b++) {
            f32x4 z = {0.f, 0.f, 0.f, 0.f};
            accG[a][b] = z; accU[a][b] = z;
        }

    const int arow = tid >> 2, akq = tid & 3;
    const int f4 = tid & 15, dq = tid >> 4;
    const int fb = f4 * 4, dd = dq * 4;
    const int gcol = f0 + fb;
    const bool bval = gcol < F_;
    const float* WgE = Wg + (size_t)e * D_ * F_;
    const float* WuE = Wu + (size_t)e * D_ * F_;

    for (int kc = 0; kc < D_; kc += 64) {
        // ---- stage A (gathered rows, fp32 -> bf16) ----
#pragma unroll
        for (int rep = 0; rep < 2; rep++) {
            int row = arow + rep * 64;
            int t = tokS[row];
            const float* src = x + (size_t)(t < 0 ? 0 : t) * D_ + kc;
#pragma unroll
            for (int s = 0; s < 4; s++) {
                int k = akq * 4 + s * 16;
                fvec4 v = {0.f, 0.f, 0.f, 0.f};
                if (t >= 0) v = *(const fvec4*)(src + k);
                usvec4 p = {f2bf(v[0]), f2bf(v[1]), f2bf(v[2]), f2bf(v[3])};
                *(usvec4*)&As[row * 72 + k] = p;
            }
        }
        // ---- stage B transposed: Bt[f][k], k contiguous ----
        {
            fvec4 vg[4], vu[4];
#pragma unroll
            for (int r = 0; r < 4; r++) {
                fvec4 zg = {0.f, 0.f, 0.f, 0.f};
                vg[r] = zg; vu[r] = zg;
                if (bval) {
                    size_t off = (size_t)(kc + dd + r) * F_ + gcol;
                    vg[r] = *(const fvec4*)(WgE + off);
                    vu[r] = *(const fvec4*)(WuE + off);
                }
            }
#pragma unroll
            for (int i = 0; i < 4; i++) {
                usvec4 pg = {f2bf(vg[0][i]), f2bf(vg[1][i]), f2bf(vg[2][i]), f2bf(vg[3][i])};
                usvec4 pu = {f2bf(vu[0][i]), f2bf(vu[1][i]), f2bf(vu[2][i]), f2bf(vu[3][i])};
                *(usvec4*)&Bgs[(fb + i) * 72 + dd] = pg;
                *(usvec4*)&Bus[(fb + i) * 72 + dd] = pu;
            }
        }
        __syncthreads();
        // ---- compute ----
#pragma unroll
        for (int kk = 0; kk < 64; kk += 32) {
            bf16x8 a[4], bg[2], bu[2];
#pragma unroll
            for (int mi = 0; mi < 4; mi++)
                a[mi] = *(const bf16x8*)&As[(wm * 64 + mi * 16 + (lane & 15)) * 72 + kk + ((lane >> 4) << 3)];
#pragma unroll
            for (int ni = 0; ni < 2; ni++) {
                int off = (wn * 32 + ni * 16 + (lane & 15)) * 72 + kk + ((lane >> 4) << 3);
                bg[ni] = *(const bf16x8*)&Bgs[off];
                bu[ni] = *(const bf16x8*)&Bus[off];
            }
#pragma unroll
            for (int mi = 0; mi < 4; mi++)
#pragma unroll
                for (int ni = 0; ni < 2; ni++) {
                    accG[mi][ni] = __builtin_amdgcn_mfma_f32_16x16x32_bf16(a[mi], bg[ni], accG[mi][ni], 0, 0, 0);
                    accU[mi][ni] = __builtin_amdgcn_mfma_f32_16x16x32_bf16(a[mi], bu[ni], accU[mi][ni], 0, 0, 0);
                }
        }
        __syncthreads();
    }
    // ---- epilogue: fused SwiGLU, write bf16 H ----
#pragma unroll
    for (int mi = 0; mi < 4; mi++)
#pragma unroll
        for (int ni = 0; ni < 2; ni++) {
            int f = f0 + wn * 32 + ni * 16 + (lane & 15);
            if (f >= F_) continue;
            int rowb = m0 + wm * 64 + mi * 16 + ((lane >> 4) << 2);
#pragma unroll
            for (int q = 0; q < 4; q++) {
                float g = accG[mi][ni][q], u = accU[mi][ni][q];
                float h = g * u / (1.f + __expf(-g));
                H[(size_t)(e * CAP_ + rowb + q) * F_ + f] = f2bf(h);
            }
        }
}

// ---------------- GEMM2: Y = H * Wd, scatter * score ----------------
__global__ __launch_bounds__(256, 2) void k_gemm2(
    const unsigned short* __restrict__ H, const float* __restrict__ Wd,
    const int* __restrict__ slot_token, const int* __restrict__ cnt,
    const float* __restrict__ scores, float* __restrict__ y) {
    const int e = blockIdx.z, m0 = blockIdx.y * 128, d0 = blockIdx.x * 64;
    if (m0 >= cnt[e]) return;

    __shared__ __align__(16) unsigned short As[128 * 72];
    __shared__ __align__(16) unsigned short Bts[64 * 72];
    __shared__ int tokS[128];
    __shared__ float scS[128];

    const int tid = threadIdx.x;
    const int lane = tid & 63, wave = tid >> 6;
    const int wm = wave >> 1, wn = wave & 1;

    if (tid < 128) {
        int t = slot_token[e * CAP_ + m0 + tid];
        tokS[tid] = t;
        scS[tid] = (t >= 0) ? scores[t] : 0.f;
    }
    __syncthreads();

    f32x4 acc[4][2];
#pragma unroll
    for (int a = 0; a < 4; a++)
#pragma unroll
        for (int b = 0; b < 2; b++) {
            f32x4 z = {0.f, 0.f, 0.f, 0.f};
            acc[a][b] = z;
        }

    const int arow = tid >> 2, akq = tid & 3;
    const int f4 = tid & 15, dq = tid >> 4;
    const int fb = f4 * 4, dd = dq * 4;
    const int gcol = d0 + fb;
    const float* WdE = Wd + (size_t)e * F_ * D_;

    for (int kc = 0; kc < 704; kc += 64) {   // 11 steps cover K = 688
        // ---- stage A from H (already bf16) ----
#pragma unroll
        for (int rep = 0; rep < 2; rep++) {
            int row = arow + rep * 64;
            size_t slot = (size_t)(e * CAP_ + m0 + row);
#pragma unroll
            for (int s = 0; s < 4; s++) {
                int k = akq * 4 + s * 16;
                usvec4 hv = {0, 0, 0, 0};
                if (kc + k < F_) hv = *(const usvec4*)&H[slot * F_ + kc + k];
                *(usvec4*)&As[row * 72 + k] = hv;
            }
        }
        // ---- stage B transposed (Wd rows are K) ----
        {
            fvec4 vd[4];
#pragma unroll
            for (int r = 0; r < 4; r++) {
                fvec4 z = {0.f, 0.f, 0.f, 0.f};
                vd[r] = z;
                int kr = kc + dd + r;
                if (kr < F_) vd[r] = *(const fvec4*)(WdE + (size_t)kr * D_ + gcol);
            }
#pragma unroll
            for (int i = 0; i < 4; i++) {
                usvec4 pd = {f2bf(vd[0][i]), f2bf(vd[1][i]), f2bf(vd[2][i]), f2bf(vd[3][i])};
                *(usvec4*)&Bts[(fb + i) * 72 + dd] = pd;
            }
        }
        __syncthreads();
#pragma unroll
        for (int kk = 0; kk < 64; kk += 32) {
            bf16x8 a[4], b[2];
#pragma unroll
            for (int mi = 0; mi < 4; mi++)
                a[mi] = *(const bf16x8*)&As[(wm * 64 + mi * 16 + (lane & 15)) * 72 + kk + ((lane >> 4) << 3)];
#pragma unroll
            for (int ni = 0; ni < 2; ni++)
                b[ni] = *(const bf16x8*)&Bts[(wn * 32 + ni * 16 + (lane & 15)) * 72 + kk + ((lane >> 4) << 3)];
#pragma unroll
            for (int mi = 0; mi < 4; mi++)
#pragma unroll
                for (int ni = 0; ni < 2; ni++)
                    acc[mi][ni] = __builtin_amdgcn_mfma_f32_16x16x32_bf16(a[mi], b[ni], acc[mi][ni], 0, 0, 0);
        }
        __syncthreads();
    }
    // ---- epilogue: scale by score, scatter to token rows ----
#pragma unroll
    for (int mi = 0; mi < 4; mi++)
#pragma unroll
        for (int ni = 0; ni < 2; ni++) {
            int d = d0 + wn * 32 + ni * 16 + (lane & 15);
            int rowb = wm * 64 + mi * 16 + ((lane >> 4) << 2);
#pragma unroll
            for (int q = 0; q < 4; q++) {
                int row = rowb + q;
                int t = tokS[row];
                if (t >= 0) y[(size_t)t * D_ + d] = acc[mi][ni][q] * scS[row];
            }
        }
}

extern "C" void kernel_launch(void* const* d_in, const int* in_sizes, int n_in,
                              void* d_out, int out_size, void* d_ws, size_t ws_size,
                              hipStream_t stream) {
    const float* x   = (const float*)d_in[0];
    const int*   idx = (const int*)d_in[1];
    const float* sc  = (const float*)d_in[2];
    const float* Wg  = (const float*)d_in[3];
    const float* Wu  = (const float*)d_in[4];
    const float* Wd  = (const float*)d_in[5];
    float* y = (float*)d_out;

    char* ws = (char*)d_ws;
    int* slot_token = (int*)ws;                              // E*CAP ints   = 40960 B
    int* row_of     = (int*)(ws + 40960);                    // N ints       = 32768 B
    int* cnt        = (int*)(ws + 40960 + 32768);            // E ints
    unsigned short* H = (unsigned short*)(ws + 131072);      // E*CAP*F bf16 = 14.09 MB

    k_dispatch<<<1, 256, 0, stream>>>(idx, slot_token, row_of, cnt);
    k_zero_dropped<<<N_, 256, 0, stream>>>(row_of, y);
    k_gemm1<<<dim3(11, 5, E_), 256, 0, stream>>>(x, Wg, Wu, slot_token, cnt, H);
    k_gemm2<<<dim3(64, 5, E_), 256, 0, stream>>>(H, Wd, slot_token, cnt, sc, y);
}

// Round 2
// 482.914 us; speedup vs baseline: 1.3811x; 1.3811x over previous
//
#include <hip/hip_runtime.h>
#include <hip/hip_bf16.h>

#define E_ 16
#define D_ 4096
#define F_ 688
#define N_ 8192
#define CAP_ 640   // int(1.25 * 8192 / 16)

typedef __attribute__((ext_vector_type(8))) short bf16x8;
typedef __attribute__((ext_vector_type(4))) float f32x4;
typedef __attribute__((ext_vector_type(4))) float fvec4;
typedef __attribute__((ext_vector_type(4))) unsigned short usvec4;
typedef __attribute__((ext_vector_type(8))) unsigned short usvec8;

__device__ __forceinline__ unsigned short f2bf(float f) {
    __hip_bfloat16 h = __float2bfloat16(f);
    return __builtin_bit_cast(unsigned short, h);
}

// ---------------- dispatch: stable per-expert positions ----------------
__global__ void k_dispatch(const int* __restrict__ idx,
                           int* __restrict__ slot_token,
                           int* __restrict__ row_of,
                           int* __restrict__ cnt) {
    __shared__ int hist[256][E_];
    const int t = threadIdx.x;
#pragma unroll
    for (int e = 0; e < E_; e++) hist[t][e] = 0;
    __syncthreads();
    const int base = t * (N_ / 256);
    for (int j = 0; j < N_ / 256; j++) {
        int e = idx[base + j];
        hist[t][e]++;
    }
    __syncthreads();
    if (t < E_) {
        int run = 0;
        for (int i = 0; i < 256; i++) { int v = hist[i][t]; hist[i][t] = run; run += v; }
        cnt[t] = run < CAP_ ? run : CAP_;
    }
    for (int s = t; s < E_ * CAP_; s += 256) slot_token[s] = -1;
    __syncthreads();
    for (int j = 0; j < N_ / 256; j++) {
        int i = base + j;
        int e = idx[i];
        int p = hist[t][e]++;
        if (p < CAP_) { slot_token[e * CAP_ + p] = i; row_of[i] = e * CAP_ + p; }
        else          { row_of[i] = -1; }
    }
}

// ---------------- zero the (rare) dropped-token rows ----------------
__global__ void k_zero_dropped(const int* __restrict__ row_of, float* __restrict__ y) {
    const int i = blockIdx.x;
    if (row_of[i] >= 0) return;
    fvec4* yp = (fvec4*)(y + (size_t)i * D_);
    fvec4 z = {0.f, 0.f, 0.f, 0.f};
    for (int c = threadIdx.x; c < D_ / 4; c += 256) yp[c] = z;
}

// ---------------- gather x -> bf16 Abuf[E*CAP][D] ----------------
__global__ void k_gather(const float* __restrict__ x, const int* __restrict__ slot_token,
                         unsigned short* __restrict__ Abuf) {
    const int slot = blockIdx.x;
    const int t = slot_token[slot];
    usvec8* dst = (usvec8*)(Abuf + (size_t)slot * D_);
    if (t < 0) {
        usvec8 z = {0, 0, 0, 0, 0, 0, 0, 0};
        for (int c = threadIdx.x; c < D_ / 8; c += 256) dst[c] = z;
    } else {
        const fvec4* src = (const fvec4*)(x + (size_t)t * D_);
        for (int c = threadIdx.x; c < D_ / 8; c += 256) {
            fvec4 a = src[2 * c], b = src[2 * c + 1];
            usvec8 p = {f2bf(a[0]), f2bf(a[1]), f2bf(a[2]), f2bf(a[3]),
                        f2bf(b[0]), f2bf(b[1]), f2bf(b[2]), f2bf(b[3])};
            dst[c] = p;
        }
    }
}

// ---------------- GEMM1: H = silu(X*Wg) * (X*Wu), bf16 out ----------------
// XCD-chunked swizzle: each XCD owns 22 consecutive (e,f) groups (= 2 experts);
// the 5 m-blocks of one group are consecutive on that XCD -> weight panel
// fetched once into the XCD's L2, hit by the other 4.
template <bool PRE>
__global__ __launch_bounds__(256, 4) void k_gemm1(
    const float* __restrict__ x, const unsigned short* __restrict__ Abuf,
    const float* __restrict__ Wg, const float* __restrict__ Wu,
    const int* __restrict__ slot_token, const int* __restrict__ cnt,
    unsigned short* __restrict__ H) {
    const int bid = blockIdx.x;           // 880 = 8 xcd * 22 groups * 5 m
    const int xcd = bid & 7;
    const int j = bid >> 3;               // 0..109
    const int mb = j % 5;
    const int gl = j / 5;                 // 0..21
    const int group = xcd * 22 + gl;      // 0..175
    const int e = group / 11, fidx = group % 11;
    const int m0 = mb * 128, f0 = fidx * 64;
    if (m0 >= cnt[e]) return;

    __shared__ __align__(16) unsigned short As[128 * 72];
    __shared__ __align__(16) unsigned short Bgs[64 * 72];
    __shared__ __align__(16) unsigned short Bus[64 * 72];
    __shared__ int tokS[128];

    const int tid = threadIdx.x;
    const int lane = tid & 63, wave = tid >> 6;
    const int wm = wave >> 1, wn = wave & 1;

    if (!PRE && tid < 128) tokS[tid] = slot_token[e * CAP_ + m0 + tid];
    if (!PRE) __syncthreads();

    f32x4 accG[4][2], accU[4][2];
#pragma unroll
    for (int a = 0; a < 4; a++)
#pragma unroll
        for (int b = 0; b < 2; b++) {
            f32x4 z = {0.f, 0.f, 0.f, 0.f};
            accG[a][b] = z; accU[a][b] = z;
        }

    const int f4 = tid & 15, dq = tid >> 4;
    const int fb = f4 * 4, dd = dq * 4;
    const int gcol = f0 + fb;
    const bool bval = gcol < F_;
    const float* WgE = Wg + (size_t)e * D_ * F_;
    const float* WuE = Wu + (size_t)e * D_ * F_;
    const unsigned short* Ae = Abuf + (size_t)(e * CAP_ + m0) * D_;

    for (int kc = 0; kc < D_; kc += 64) {
        // ---- stage A ----
        if (PRE) {
            const int arow = tid >> 1;            // 0..127
            const int ak0 = (tid & 1) * 32;       // 64B contiguous per thread
#pragma unroll
            for (int s = 0; s < 4; s++) {
                int k = ak0 + s * 8;
                *(usvec8*)&As[arow * 72 + k] = *(const usvec8*)&Ae[(size_t)arow * D_ + kc + k];
            }
        } else {
            const int arow = tid >> 2, akq = tid & 3;
#pragma unroll
            for (int rep = 0; rep < 2; rep++) {
                int row = arow + rep * 64;
                int t = tokS[row];
                const float* src = x + (size_t)(t < 0 ? 0 : t) * D_ + kc;
#pragma unroll
                for (int s = 0; s < 4; s++) {
                    int k = akq * 4 + s * 16;
                    fvec4 v = {0.f, 0.f, 0.f, 0.f};
                    if (t >= 0) v = *(const fvec4*)(src + k);
                    usvec4 p = {f2bf(v[0]), f2bf(v[1]), f2bf(v[2]), f2bf(v[3])};
                    *(usvec4*)&As[row * 72 + k] = p;
                }
            }
        }
        // ---- stage B transposed: Bt[f][k], k contiguous ----
        {
            fvec4 vg[4], vu[4];
#pragma unroll
            for (int r = 0; r < 4; r++) {
                fvec4 zg = {0.f, 0.f, 0.f, 0.f};
                vg[r] = zg; vu[r] = zg;
                if (bval) {
                    size_t off = (size_t)(kc + dd + r) * F_ + gcol;
                    vg[r] = *(const fvec4*)(WgE + off);
                    vu[r] = *(const fvec4*)(WuE + off);
                }
            }
#pragma unroll
            for (int i = 0; i < 4; i++) {
                usvec4 pg = {f2bf(vg[0][i]), f2bf(vg[1][i]), f2bf(vg[2][i]), f2bf(vg[3][i])};
                usvec4 pu = {f2bf(vu[0][i]), f2bf(vu[1][i]), f2bf(vu[2][i]), f2bf(vu[3][i])};
                *(usvec4*)&Bgs[(fb + i) * 72 + dd] = pg;
                *(usvec4*)&Bus[(fb + i) * 72 + dd] = pu;
            }
        }
        __syncthreads();
        // ---- compute ----
#pragma unroll
        for (int kk = 0; kk < 64; kk += 32) {
            bf16x8 a[4], bg[2], bu[2];
#pragma unroll
            for (int mi = 0; mi < 4; mi++)
                a[mi] = *(const bf16x8*)&As[(wm * 64 + mi * 16 + (lane & 15)) * 72 + kk + ((lane >> 4) << 3)];
#pragma unroll
            for (int ni = 0; ni < 2; ni++) {
                int off = (wn * 32 + ni * 16 + (lane & 15)) * 72 + kk + ((lane >> 4) << 3);
                bg[ni] = *(const bf16x8*)&Bgs[off];
                bu[ni] = *(const bf16x8*)&Bus[off];
            }
#pragma unroll
            for (int mi = 0; mi < 4; mi++)
#pragma unroll
                for (int ni = 0; ni < 2; ni++) {
                    accG[mi][ni] = __builtin_amdgcn_mfma_f32_16x16x32_bf16(a[mi], bg[ni], accG[mi][ni], 0, 0, 0);
                    accU[mi][ni] = __builtin_amdgcn_mfma_f32_16x16x32_bf16(a[mi], bu[ni], accU[mi][ni], 0, 0, 0);
                }
        }
        __syncthreads();
    }
    // ---- epilogue: fused SwiGLU, write bf16 H ----
#pragma unroll
    for (int mi = 0; mi < 4; mi++)
#pragma unroll
        for (int ni = 0; ni < 2; ni++) {
            int f = f0 + wn * 32 + ni * 16 + (lane & 15);
            if (f >= F_) continue;
            int rowb = m0 + wm * 64 + mi * 16 + ((lane >> 4) << 2);
#pragma unroll
            for (int q = 0; q < 4; q++) {
                float g = accG[mi][ni][q], u = accU[mi][ni][q];
                float h = g * u / (1.f + __expf(-g));
                H[(size_t)(e * CAP_ + rowb + q) * F_ + f] = f2bf(h);
            }
        }
}

// ---------------- GEMM2: Y = H * Wd, scatter * score ----------------
__global__ __launch_bounds__(256, 4) void k_gemm2(
    const unsigned short* __restrict__ H, const float* __restrict__ Wd,
    const int* __restrict__ slot_token, const int* __restrict__ cnt,
    const float* __restrict__ scores, float* __restrict__ y) {
    const int bid = blockIdx.x;           // 5120 = 8 xcd * 128 groups * 5 m
    const int xcd = bid & 7;
    const int j = bid >> 3;               // 0..639
    const int mb = j % 5;
    const int gl = j / 5;                 // 0..127
    const int group = xcd * 128 + gl;     // 0..1023
    const int e = group >> 6, didx = group & 63;
    const int m0 = mb * 128, d0 = didx * 64;
    if (m0 >= cnt[e]) return;

    __shared__ __align__(16) unsigned short As[128 * 72];
    __shared__ __align__(16) unsigned short Bts[64 * 72];
    __shared__ int tokS[128];
    __shared__ float scS[128];

    const int tid = threadIdx.x;
    const int lane = tid & 63, wave = tid >> 6;
    const int wm = wave >> 1, wn = wave & 1;

    if (tid < 128) {
        int t = slot_token[e * CAP_ + m0 + tid];
        tokS[tid] = t;
        scS[tid] = (t >= 0) ? scores[t] : 0.f;
    }
    __syncthreads();

    f32x4 acc[4][2];
#pragma unroll
    for (int a = 0; a < 4; a++)
#pragma unroll
        for (int b = 0; b < 2; b++) {
            f32x4 z = {0.f, 0.f, 0.f, 0.f};
            acc[a][b] = z;
        }

    const int arow = tid >> 2, akq = tid & 3;
    const int f4 = tid & 15, dq = tid >> 4;
    const int fb = f4 * 4, dd = dq * 4;
    const int gcol = d0 + fb;
    const float* WdE = Wd + (size_t)e * F_ * D_;

    for (int kc = 0; kc < 704; kc += 64) {   // 11 steps cover K = 688
        // ---- stage A from H (already bf16) ----
#pragma unroll
        for (int rep = 0; rep < 2; rep++) {
            int row = arow + rep * 64;
            size_t slot = (size_t)(e * CAP_ + m0 + row);
#pragma unroll
            for (int s = 0; s < 4; s++) {
                int k = akq * 4 + s * 16;
                usvec4 hv = {0, 0, 0, 0};
                if (kc + k < F_) hv = *(const usvec4*)&H[slot * F_ + kc + k];
                *(usvec4*)&As[row * 72 + k] = hv;
            }
        }
        // ---- stage B transposed (Wd rows are K) ----
        {
            fvec4 vd[4];
#pragma unroll
            for (int r = 0; r < 4; r++) {
                fvec4 z = {0.f, 0.f, 0.f, 0.f};
                vd[r] = z;
                int kr = kc + dd + r;
                if (kr < F_) vd[r] = *(const fvec4*)(WdE + (size_t)kr * D_ + gcol);
            }
#pragma unroll
            for (int i = 0; i < 4; i++) {
                usvec4 pd = {f2bf(vd[0][i]), f2bf(vd[1][i]), f2bf(vd[2][i]), f2bf(vd[3][i])};
                *(usvec4*)&Bts[(fb + i) * 72 + dd] = pd;
            }
        }
        __syncthreads();
#pragma unroll
        for (int kk = 0; kk < 64; kk += 32) {
            bf16x8 a[4], b[2];
#pragma unroll
            for (int mi = 0; mi < 4; mi++)
                a[mi] = *(const bf16x8*)&As[(wm * 64 + mi * 16 + (lane & 15)) * 72 + kk + ((lane >> 4) << 3)];
#pragma unroll
            for (int ni = 0; ni < 2; ni++)
                b[ni] = *(const bf16x8*)&Bts[(wn * 32 + ni * 16 + (lane & 15)) * 72 + kk + ((lane >> 4) << 3)];
#pragma unroll
            for (int mi = 0; mi < 4; mi++)
#pragma unroll
                for (int ni = 0; ni < 2; ni++)
                    acc[mi][ni] = __builtin_amdgcn_mfma_f32_16x16x32_bf16(a[mi], b[ni], acc[mi][ni], 0, 0, 0);
        }
        __syncthreads();
    }
    // ---- epilogue: scale by score, scatter to token rows ----
#pragma unroll
    for (int mi = 0; mi < 4; mi++)
#pragma unroll
        for (int ni = 0; ni < 2; ni++) {
            int d = d0 + wn * 32 + ni * 16 + (lane & 15);
            int rowb = wm * 64 + mi * 16 + ((lane >> 4) << 2);
#pragma unroll
            for (int q = 0; q < 4; q++) {
                int row = rowb + q;
                int t = tokS[row];
                if (t >= 0) y[(size_t)t * D_ + d] = acc[mi][ni][q] * scS[row];
            }
        }
}

extern "C" void kernel_launch(void* const* d_in, const int* in_sizes, int n_in,
                              void* d_out, int out_size, void* d_ws, size_t ws_size,
                              hipStream_t stream) {
    const float* x   = (const float*)d_in[0];
    const int*   idx = (const int*)d_in[1];
    const float* sc  = (const float*)d_in[2];
    const float* Wg  = (const float*)d_in[3];
    const float* Wu  = (const float*)d_in[4];
    const float* Wd  = (const float*)d_in[5];
    float* y = (float*)d_out;

    char* ws = (char*)d_ws;
    int* slot_token = (int*)ws;                              // E*CAP ints   = 40960 B
    int* row_of     = (int*)(ws + 40960);                    // N ints       = 32768 B
    int* cnt        = (int*)(ws + 40960 + 32768);            // E ints
    const size_t hoff = 131072;
    const size_t hbytes = (size_t)E_ * CAP_ * F_ * 2;        // 14,090,240 B
    unsigned short* H = (unsigned short*)(ws + hoff);
    const size_t aoff = hoff + hbytes;                       // 16-aligned
    const size_t abytes = (size_t)E_ * CAP_ * D_ * 2;        // 83,886,080 B
    unsigned short* Abuf = (unsigned short*)(ws + aoff);
    const bool pre = ws_size >= aoff + abytes;

    k_dispatch<<<1, 256, 0, stream>>>(idx, slot_token, row_of, cnt);
    k_zero_dropped<<<N_, 256, 0, stream>>>(row_of, y);
    if (pre) {
        k_gather<<<E_ * CAP_, 256, 0, stream>>>(x, slot_token, Abuf);
        k_gemm1<true><<<880, 256, 0, stream>>>(x, Abuf, Wg, Wu, slot_token, cnt, H);
    } else {
        k_gemm1<false><<<880, 256, 0, stream>>>(x, Abuf, Wg, Wu, slot_token, cnt, H);
    }
    k_gemm2<<<5120, 256, 0, stream>>>(H, Wd, slot_token, cnt, sc, y);
}